// Round 11
// baseline (406.972 us; speedup 1.0000x reference)
//
#include <hip/hip_runtime.h>
#include <cstdint>
#include <cstddef>

#define M_DIM 4096
#define N_DIM 8192
#define K_DIM 4096

typedef __attribute__((ext_vector_type(4))) int int4v;
typedef __attribute__((ext_vector_type(16))) int int16v;

// ---------------------------------------------------------------------------
// Pack int32 -> int8 in 32x32x32-i8 MFMA fragment order (R10-verified).
// p = 32-row panel, s = 32-byte kstep. chunk(p,s) = 1024 B where lane l
// holds row 32p+(l&31), k-bytes s*32 + (l>>5)*16 .. +16.
// Panel stride = 32*K = 131072 B.
// ---------------------------------------------------------------------------
__global__ void __launch_bounds__(256) pack_frag(const int* __restrict__ a,
                                                 const int* __restrict__ b,
                                                 unsigned char* __restrict__ pa,
                                                 unsigned char* __restrict__ pb) {
    size_t t = (size_t)blockIdx.x * 256 + threadIdx.x;
    const size_t NA = (size_t)(M_DIM / 32) * (K_DIM / 32) * 64;
    const int* __restrict__ src;
    unsigned char* __restrict__ dst;
    if (t < NA) {
        src = a; dst = pa;
    } else {
        src = b; dst = pb; t -= NA;
    }
    const int l = (int)(t & 63);
    const int s = (int)((t >> 6) & (K_DIM / 32 - 1));
    const int p = (int)(t >> 13);
    const int* g = src + ((size_t)(32 * p + (l & 31))) * K_DIM + s * 32 + (l >> 5) * 16;
    const int4v* g4 = (const int4v*)g;
    int4v o;
#pragma unroll
    for (int q = 0; q < 4; ++q) {
        int4v v = g4[q];
        o[q] = (v[0] & 0xff) | ((v[1] & 0xff) << 8) | ((v[2] & 0xff) << 16) | (v[3] << 24);
    }
    ((int4v*)dst)[t] = o;
}

// ---------------------------------------------------------------------------
// GEMM: block 256x256, 256 thr = 4 waves at 1 wave/SIMD, wave tile 128x128
// (4 A-panels x 4 B-panels of 32). mfma_i32_32x32x32_i8 via INLINE ASM with
// "+a" accumulator constraint: pins acc[4][4] (256 regs) into AGPRs, leaving
// the VGPR file for TWO fragment register sets + addressing (R9's spill
// failure was the allocator refusing this partition with builtins).
// Per 2-iter window: read frags(T), issue frags(T+1) reads, 32 MFMA on T
// (reads of T+1 complete underneath, in-order lgkm), 32 MFMA on T+1, barrier.
// LDS quad-buffered (4 x 32 KB), staging 2 iters ahead (R8 structure).
// ---------------------------------------------------------------------------
__device__ inline void async_copy16(const unsigned char* g, unsigned char* l) {
    __builtin_amdgcn_global_load_lds(
        (const __attribute__((address_space(1))) void*)g,
        (__attribute__((address_space(3))) void*)l,
        16, 0, 0);
}

__device__ inline void mfma32(int16v& acc, int4v av, int4v bv) {
    asm("v_mfma_i32_32x32x32_i8 %0, %1, %2, %0" : "+a"(acc) : "v"(av), "v"(bv));
}

__global__ void __launch_bounds__(256, 1) gemm_i8(const unsigned char* __restrict__ Ap,
                                                  const unsigned char* __restrict__ Bp,
                                                  const _Float16* __restrict__ arow,
                                                  const _Float16* __restrict__ acol,
                                                  _Float16* __restrict__ Cout) {
    __shared__ __align__(16) unsigned char As[4 * 16384];
    __shared__ __align__(16) unsigned char Bs[4 * 16384];

    const int tid  = threadIdx.x;
    const int lane = tid & 63;
    const int wave = tid >> 6;        // 0..3
    const int bn   = blockIdx.x;      // 0..31 (256 cols)
    const int bm   = blockIdx.y;      // 0..15 (256 rows)

    const int pm0 = (wave & 1) * 4;   // A panel base (4 panels of 32 = 128 rows)
    const int pn0 = (wave >> 1) * 4;  // B panel base (4 panels of 32 = 128 cols)

    // staging: wave w stages A panels {2w,2w+1} and B panels {2w,2w+1};
    // per iter t: ksteps {2t,2t+1} -> global byte offset t*2048 + u*1024.
    const unsigned char* ag[2];
    const unsigned char* bg[2];
    int slo[2];
#pragma unroll
    for (int r = 0; r < 2; ++r) {
        const int p = 2 * wave + r;
        ag[r]  = Ap + (size_t)(bm * 8 + p) * 131072 + lane * 16;
        bg[r]  = Bp + (size_t)(bn * 8 + p) * 131072 + lane * 16;
        slo[r] = p * 2048;  // wave-uniform; HW adds lane*16
    }

    const int a_off = pm0 * 2048 + lane * 16;  // + i*2048 + u*1024
    const int b_off = pn0 * 2048 + lane * 16;  // + j*2048 + u*1024

    int16v acc[4][4];
#pragma unroll
    for (int i = 0; i < 4; ++i)
#pragma unroll
        for (int j = 0; j < 4; ++j) acc[i][j] = (int16v)0;

    const int NT = K_DIM / 64;  // 64 iters (BK=64 = 2 ksteps of 32)

    // prologue: stage T=0 -> buf0, T=1 -> buf1
#pragma unroll
    for (int t = 0; t < 2; ++t)
#pragma unroll
        for (int r = 0; r < 2; ++r)
#pragma unroll
            for (int u = 0; u < 2; ++u) {
                async_copy16(ag[r] + t * 2048 + u * 1024,
                             As + t * 16384 + slo[r] + u * 1024);
                async_copy16(bg[r] + t * 2048 + u * 1024,
                             Bs + t * 16384 + slo[r] + u * 1024);
            }
    __syncthreads();

    for (int T = 0; T < NT; T += 2) {
        // stage T+2, T+3 (drained at this window's barrier)
        if (T + 2 < NT) {
#pragma unroll
            for (int w = 2; w < 4; ++w) {
                const size_t gko = (size_t)(T + w) * 2048;
                const int buf = ((T + w) & 3) * 16384;
#pragma unroll
                for (int r = 0; r < 2; ++r)
#pragma unroll
                    for (int u = 0; u < 2; ++u) {
                        async_copy16(ag[r] + gko + u * 1024, As + buf + slo[r] + u * 1024);
                        async_copy16(bg[r] + gko + u * 1024, Bs + buf + slo[r] + u * 1024);
                    }
            }
        }

        const int c0 = (T & 3) * 16384;
        const int c1 = ((T + 1) & 3) * 16384;

        // fragment set 0 (iter T) and set 1 (iter T+1); 16 ds_read_b128 each.
        int4v a0[8], b0[8], a1[8], b1[8];
#pragma unroll
        for (int i = 0; i < 4; ++i)
#pragma unroll
            for (int u = 0; u < 2; ++u) {
                a0[i * 2 + u] = *(const int4v*)(As + c0 + a_off + i * 2048 + u * 1024);
                b0[i * 2 + u] = *(const int4v*)(Bs + c0 + b_off + i * 2048 + u * 1024);
            }
#pragma unroll
        for (int i = 0; i < 4; ++i)
#pragma unroll
            for (int u = 0; u < 2; ++u) {
                a1[i * 2 + u] = *(const int4v*)(As + c1 + a_off + i * 2048 + u * 1024);
                b1[i * 2 + u] = *(const int4v*)(Bs + c1 + b_off + i * 2048 + u * 1024);
            }

        // MFMA burst for iter T (set-1 reads complete underneath)
#pragma unroll
        for (int u = 0; u < 2; ++u)
#pragma unroll
            for (int i = 0; i < 4; ++i)
#pragma unroll
                for (int j = 0; j < 4; ++j)
                    mfma32(acc[i][j], a0[i * 2 + u], b0[j * 2 + u]);
        // MFMA burst for iter T+1
#pragma unroll
        for (int u = 0; u < 2; ++u)
#pragma unroll
            for (int i = 0; i < 4; ++i)
#pragma unroll
                for (int j = 0; j < 4; ++j)
                    mfma32(acc[i][j], a1[i * 2 + u], b1[j * 2 + u]);

        __syncthreads();
    }

    // hazard insurance: MFMA(AGPR write) -> v_accvgpr_read in epilogue
    asm volatile("s_nop 7\n\ts_nop 7" ::);

    // --- epilogue: 32x32 C/D layout (verified m74/m101, R10):
    // col = lane&31, row = (reg&3) + 8*(reg>>2) + 4*(lane>>5)
    const int gcol0 = bn * 256 + pn0 * 32 + (lane & 31);
    float ac4[4];
#pragma unroll
    for (int j = 0; j < 4; ++j) ac4[j] = (float)acol[gcol0 + j * 32];

    const size_t rbase = (size_t)bm * 256 + pm0 * 32 + 4 * (lane >> 5);
#pragma unroll
    for (int i = 0; i < 4; ++i) {
#pragma unroll
        for (int r = 0; r < 16; ++r) {
            const size_t row = rbase + i * 32 + (r & 3) + 8 * (r >> 2);
            const float ar = (float)arow[row];
            _Float16* outp = Cout + row * (size_t)N_DIM + gcol0;
#pragma unroll
            for (int j = 0; j < 4; ++j) {
                float v = (float)acc[i][j][r] * ar * ac4[j];
                outp[j * 32] = (_Float16)v;
            }
        }
    }
}

// ---------------------------------------------------------------------------
extern "C" void kernel_launch(void* const* d_in, const int* in_sizes, int n_in,
                              void* d_out, int out_size, void* d_ws, size_t ws_size,
                              hipStream_t stream) {
    const int* a = (const int*)d_in[0];             // [M,K] int32 (int8 values)
    const int* b = (const int*)d_in[1];             // [N,K] int32 (int8 values)
    const _Float16* ar = (const _Float16*)d_in[2];  // [M] fp16
    const _Float16* ac = (const _Float16*)d_in[3];  // [N] fp16
    _Float16* out = (_Float16*)d_out;               // [M,N] fp16

    unsigned char* pa = (unsigned char*)d_ws;        // 16 MB
    unsigned char* pb = pa + (size_t)M_DIM * K_DIM;  // 32 MB

    const size_t total_frag = (size_t)(M_DIM / 32 + N_DIM / 32) * (K_DIM / 32) * 64;
    pack_frag<<<(int)(total_frag / 256), 256, 0, stream>>>(a, b, pa, pb);

    dim3 grid(N_DIM / 256, M_DIM / 256);
    gemm_i8<<<grid, 256, 0, stream>>>(pa, pb, ar, ac, out);
}

// Round 12
// 373.223 us; speedup vs baseline: 1.0904x; 1.0904x over previous
//
#include <hip/hip_runtime.h>
#include <cstdint>
#include <cstddef>

#define M_DIM 4096
#define N_DIM 8192
#define K_DIM 4096

typedef __attribute__((ext_vector_type(4))) int int4v;

// ---------------------------------------------------------------------------
// Pack into MFMA-fragment order (int32 -> int8). R3/R8-verified, identical.
// p = 16-row panel, s = 64-byte kstep, lane l: chunk(p,s) is 1024 B where
// lane l holds row 16p+(l&15), k-bytes s*64 + (l>>4)*16 .. +16.
// ---------------------------------------------------------------------------
__global__ void __launch_bounds__(256) pack_frag(const int* __restrict__ a,
                                                 const int* __restrict__ b,
                                                 unsigned char* __restrict__ pa,
                                                 unsigned char* __restrict__ pb) {
    size_t t = (size_t)blockIdx.x * 256 + threadIdx.x;
    const size_t NA = (size_t)(M_DIM / 16) * (K_DIM / 64) * 64;
    const int* __restrict__ src;
    unsigned char* __restrict__ dst;
    if (t < NA) {
        src = a; dst = pa;
    } else {
        src = b; dst = pb; t -= NA;
    }
    const int l = (int)(t & 63);
    const int s = (int)((t >> 6) & 63);
    const int p = (int)(t >> 12);
    const int* g = src + ((size_t)(16 * p + (l & 15))) * K_DIM + s * 64 + (l >> 4) * 16;
    const int4v* g4 = (const int4v*)g;
    int4v o;
#pragma unroll
    for (int q = 0; q < 4; ++q) {
        int4v v = g4[q];
        o[q] = (v[0] & 0xff) | ((v[1] & 0xff) << 8) | ((v[2] & 0xff) << 16) | (v[3] << 24);
    }
    ((int4v*)dst)[t] = o;
}

// ---------------------------------------------------------------------------
// GEMM: block 256x256, 512 thr = 8 waves (2 waves/SIMD), wave tile 64x128
// (4 A x 8 B panels), mfma_i32_16x16x64_i8 (verified layouts), BK=64.
// R12 = R8 + explicit 2-iter fragment register pipelining: BOTH iterations'
// fragments are bulk-read (24 ds_read_b128, ~96 VGPR — acc lives in AGPRs,
// R8 showed VGPR_Count=92 so the file has room), then both MFMA bursts run.
// Burst T waits only on the first 12 reads; the second 12 complete UNDER
// burst T, overlapping ~half the per-window LDS read time.
// Quad-buffered LDS (4 x 32 KB), staging 2 iters ahead, barrier per 2 iters.
// ---------------------------------------------------------------------------
__device__ inline void async_copy16(const unsigned char* g, unsigned char* l) {
    __builtin_amdgcn_global_load_lds(
        (const __attribute__((address_space(1))) void*)g,
        (__attribute__((address_space(3))) void*)l,
        16, 0, 0);
}

__global__ void __launch_bounds__(512, 2) gemm_i8(const unsigned char* __restrict__ Ap,
                                                  const unsigned char* __restrict__ Bp,
                                                  const _Float16* __restrict__ arow,
                                                  const _Float16* __restrict__ acol,
                                                  _Float16* __restrict__ Cout) {
    __shared__ __align__(16) unsigned char As[4 * 16384];
    __shared__ __align__(16) unsigned char Bs[4 * 16384];

    const int tid  = threadIdx.x;
    const int lane = tid & 63;
    const int wave = tid >> 6;        // 0..7
    const int bn   = blockIdx.x;      // 0..31 (256 cols)
    const int bm   = blockIdx.y;      // 0..15 (256 rows)

    const int pm0 = (wave & 3) * 4;   // A panel base (4 panels = 64 rows)
    const int pn0 = (wave >> 2) * 8;  // B panel base (8 panels = 128 cols)

    // staging: wave w stages A panels {2w,2w+1} and B panels {2w,2w+1}
    const unsigned char* ag[2];
    const unsigned char* bg[2];
    int slo[2];
#pragma unroll
    for (int r = 0; r < 2; ++r) {
        const int p = 2 * wave + r;
        ag[r]  = Ap + (size_t)(bm * 16 + p) * 65536 + lane * 16;
        bg[r]  = Bp + (size_t)(bn * 16 + p) * 65536 + lane * 16;
        slo[r] = p * 1024;  // wave-uniform; HW adds lane*16
    }

    const int a_off = pm0 * 1024 + lane * 16;  // + i*1024
    const int b_off = pn0 * 1024 + lane * 16;  // + j*1024

    int4v acc[4][8];
#pragma unroll
    for (int i = 0; i < 4; ++i)
#pragma unroll
        for (int j = 0; j < 8; ++j) acc[i][j] = (int4v)0;

    const int NT = K_DIM / 64;  // 64, even

    // prologue: stage T=0 -> buf0, T=1 -> buf1
#pragma unroll
    for (int r = 0; r < 2; ++r) {
        async_copy16(ag[r], As + slo[r]);
        async_copy16(bg[r], Bs + slo[r]);
        async_copy16(ag[r] + 1024, As + 16384 + slo[r]);
        async_copy16(bg[r] + 1024, Bs + 16384 + slo[r]);
    }
    __syncthreads();

    for (int T = 0; T < NT; T += 2) {
        // stage T+2, T+3 into their ring buffers (drained at the barrier
        // below, after TWO full compute iterations)
        if (T + 2 < NT) {
            const size_t gko = (size_t)(T + 2) * 1024;
            const int buf = ((T + 2) & 3) * 16384;
#pragma unroll
            for (int r = 0; r < 2; ++r) {
                async_copy16(ag[r] + gko, As + buf + slo[r]);
                async_copy16(bg[r] + gko, Bs + buf + slo[r]);
            }
            const size_t gko3 = gko + 1024;
            const int buf3 = ((T + 3) & 3) * 16384;
#pragma unroll
            for (int r = 0; r < 2; ++r) {
                async_copy16(ag[r] + gko3, As + buf3 + slo[r]);
                async_copy16(bg[r] + gko3, Bs + buf3 + slo[r]);
            }
        }

        const int c0 = (T & 3) * 16384;
        const int c1 = ((T + 1) & 3) * 16384;

        // bulk-read BOTH iterations' fragments (both buffers already drained
        // at the previous barrier). 24 ds_read_b128, ~96 VGPR live.
        int4v af0[4], bf0[8], af1[4], bf1[8];
#pragma unroll
        for (int i = 0; i < 4; ++i)
            af0[i] = *(const int4v*)(As + c0 + a_off + i * 1024);
#pragma unroll
        for (int j = 0; j < 8; ++j)
            bf0[j] = *(const int4v*)(Bs + c0 + b_off + j * 1024);
#pragma unroll
        for (int i = 0; i < 4; ++i)
            af1[i] = *(const int4v*)(As + c1 + a_off + i * 1024);
#pragma unroll
        for (int j = 0; j < 8; ++j)
            bf1[j] = *(const int4v*)(Bs + c1 + b_off + j * 1024);

        // MFMA burst T (af1/bf1 reads complete underneath)
#pragma unroll
        for (int i = 0; i < 4; ++i)
#pragma unroll
            for (int j = 0; j < 8; ++j)
                acc[i][j] = __builtin_amdgcn_mfma_i32_16x16x64_i8(af0[i], bf0[j],
                                                                  acc[i][j], 0, 0, 0);
        // MFMA burst T+1
#pragma unroll
        for (int i = 0; i < 4; ++i)
#pragma unroll
            for (int j = 0; j < 8; ++j)
                acc[i][j] = __builtin_amdgcn_mfma_i32_16x16x64_i8(af1[i], bf1[j],
                                                                  acc[i][j], 0, 0, 0);

        __syncthreads();
    }

    // --- epilogue: C/D layout col=lane&15, row=(lane>>4)*4+reg (verified)
    const int gcol0 = bn * 256 + pn0 * 16 + (lane & 15);
    float ac8[8];
#pragma unroll
    for (int j = 0; j < 8; ++j) ac8[j] = (float)acol[gcol0 + j * 16];

    const size_t grow0 = (size_t)bm * 256 + pm0 * 16 + (lane >> 4) * 4;
#pragma unroll
    for (int i = 0; i < 4; ++i) {
#pragma unroll
        for (int r = 0; r < 4; ++r) {
            const size_t row = grow0 + i * 16 + r;
            const float ar = (float)arow[row];
            _Float16* outp = Cout + row * (size_t)N_DIM + gcol0;
#pragma unroll
            for (int j = 0; j < 8; ++j) {
                float v = (float)acc[i][j][r] * ar * ac8[j];
                outp[j * 16] = (_Float16)v;
            }
        }
    }
}

// ---------------------------------------------------------------------------
extern "C" void kernel_launch(void* const* d_in, const int* in_sizes, int n_in,
                              void* d_out, int out_size, void* d_ws, size_t ws_size,
                              hipStream_t stream) {
    const int* a = (const int*)d_in[0];             // [M,K] int32 (int8 values)
    const int* b = (const int*)d_in[1];             // [N,K] int32 (int8 values)
    const _Float16* ar = (const _Float16*)d_in[2];  // [M] fp16
    const _Float16* ac = (const _Float16*)d_in[3];  // [N] fp16
    _Float16* out = (_Float16*)d_out;               // [M,N] fp16

    unsigned char* pa = (unsigned char*)d_ws;        // 16 MB
    unsigned char* pb = pa + (size_t)M_DIM * K_DIM;  // 32 MB

    const size_t total_frag = (size_t)(M_DIM / 16 + N_DIM / 16) * (K_DIM / 64) * 64;
    pack_frag<<<(int)(total_frag / 256), 256, 0, stream>>>(a, b, pa, pb);

    dim3 grid(N_DIM / 256, M_DIM / 256);
    gemm_i8<<<grid, 512, 0, stream>>>(pa, pb, ar, ac, out);
}

// Round 13
// 372.176 us; speedup vs baseline: 1.0935x; 1.0028x over previous
//
#include <hip/hip_runtime.h>
#include <cstdint>
#include <cstddef>

#define M_DIM 4096
#define N_DIM 8192
#define K_DIM 4096

typedef __attribute__((ext_vector_type(4))) int int4v;

// ---------------------------------------------------------------------------
// Pack into MFMA-fragment order (int32 -> int8). R3/R8-verified, identical.
// p = 16-row panel, s = 64-byte kstep, lane l: chunk(p,s) is 1024 B where
// lane l holds row 16p+(l&15), k-bytes s*64 + (l>>4)*16 .. +16.
// ---------------------------------------------------------------------------
__global__ void __launch_bounds__(256) pack_frag(const int* __restrict__ a,
                                                 const int* __restrict__ b,
                                                 unsigned char* __restrict__ pa,
                                                 unsigned char* __restrict__ pb) {
    size_t t = (size_t)blockIdx.x * 256 + threadIdx.x;
    const size_t NA = (size_t)(M_DIM / 16) * (K_DIM / 64) * 64;
    const int* __restrict__ src;
    unsigned char* __restrict__ dst;
    if (t < NA) {
        src = a; dst = pa;
    } else {
        src = b; dst = pb; t -= NA;
    }
    const int l = (int)(t & 63);
    const int s = (int)((t >> 6) & 63);
    const int p = (int)(t >> 12);
    const int* g = src + ((size_t)(16 * p + (l & 15))) * K_DIM + s * 64 + (l >> 4) * 16;
    const int4v* g4 = (const int4v*)g;
    int4v o;
#pragma unroll
    for (int q = 0; q < 4; ++q) {
        int4v v = g4[q];
        o[q] = (v[0] & 0xff) | ((v[1] & 0xff) << 8) | ((v[2] & 0xff) << 16) | (v[3] << 24);
    }
    ((int4v*)dst)[t] = o;
}

// ---------------------------------------------------------------------------
// GEMM: block 128(M) x 256(N), 256 thr = 4 WAVES — half-size barrier domain.
// Wave tile 64x128 (4 A x 8 B panels), mfma_i32_16x16x64_i8, BK=64 —
// per-wave geometry/registers byte-identical to R8 (VGPR ~92, acc in AGPR).
// KEY vs R8: LDS is 48 KB/block (double buffer) so TWO blocks co-reside per
// CU with INDEPENDENT barriers. When one block's waves sit in the LDS-read/
// drain phase, the sibling block's waves keep issuing MFMAs (pipes
// co-schedule across waves, m114) — breaking the CU-wide phase-lock that
// held R6/R8/R12 at sum-of-pipes (~2520 cy/iter vs max ~1400).
// ---------------------------------------------------------------------------
__device__ inline void async_copy16(const unsigned char* g, unsigned char* l) {
    __builtin_amdgcn_global_load_lds(
        (const __attribute__((address_space(1))) void*)g,
        (__attribute__((address_space(3))) void*)l,
        16, 0, 0);
}

__global__ void __launch_bounds__(256, 2) gemm_i8(const unsigned char* __restrict__ Ap,
                                                  const unsigned char* __restrict__ Bp,
                                                  const _Float16* __restrict__ arow,
                                                  const _Float16* __restrict__ acol,
                                                  _Float16* __restrict__ Cout) {
    __shared__ __align__(16) unsigned char As[2 * 8192];   // 8 A-panels x 1 KB, x2
    __shared__ __align__(16) unsigned char Bs[2 * 16384];  // 16 B-panels x 1 KB, x2

    const int tid  = threadIdx.x;
    const int lane = tid & 63;
    const int wave = tid >> 6;        // 0..3
    const int bn   = blockIdx.x;      // 0..31 (256 cols)
    const int bm   = blockIdx.y;      // 0..31 (128 rows)

    const int pm0 = (wave & 1) * 4;   // A panel base (4 panels = 64 rows)
    const int pn0 = (wave >> 1) * 8;  // B panel base (8 panels = 128 cols)

    // staging: wave w stages A panels {2w,2w+1} (2 chunks) and
    // B panels {4w..4w+3} (4 chunks); 24 chunks = 24 KB per iter per block.
    const unsigned char* ag[2];
    int salo[2];
#pragma unroll
    for (int r = 0; r < 2; ++r) {
        const int p = 2 * wave + r;
        ag[r]   = Ap + (size_t)(bm * 8 + p) * 65536 + lane * 16;
        salo[r] = p * 1024;  // wave-uniform; HW adds lane*16
    }
    const unsigned char* bg[4];
    int sblo[4];
#pragma unroll
    for (int r = 0; r < 4; ++r) {
        const int p = 4 * wave + r;
        bg[r]   = Bp + (size_t)(bn * 16 + p) * 65536 + lane * 16;
        sblo[r] = p * 1024;
    }

    const int a_off = pm0 * 1024 + lane * 16;  // + i*1024
    const int b_off = pn0 * 1024 + lane * 16;  // + j*1024

    int4v acc[4][8];
#pragma unroll
    for (int i = 0; i < 4; ++i)
#pragma unroll
        for (int j = 0; j < 8; ++j) acc[i][j] = (int4v)0;

    const int NT = K_DIM / 64;  // 64

    // prologue: stage T=0 into buffer 0
#pragma unroll
    for (int r = 0; r < 2; ++r) async_copy16(ag[r], As + salo[r]);
#pragma unroll
    for (int r = 0; r < 4; ++r) async_copy16(bg[r], Bs + sblo[r]);
    __syncthreads();

#pragma unroll 2
    for (int T = 0; T < NT; ++T) {
        const int ca = (T & 1) * 8192;
        const int cb = (T & 1) * 16384;

        // stage T+1 into the other buffer (drained at the barrier below,
        // after this iter's full MFMA phase)
        if (T + 1 < NT) {
            const size_t gko = (size_t)(T + 1) * 1024;
#pragma unroll
            for (int r = 0; r < 2; ++r)
                async_copy16(ag[r] + gko, As + (ca ^ 8192) + salo[r]);
#pragma unroll
            for (int r = 0; r < 4; ++r)
                async_copy16(bg[r] + gko, Bs + (cb ^ 16384) + sblo[r]);
        }

        // bulk fragment reads, compiler-scheduled (R7 lesson: do not pin)
        int4v af[4], bf[8];
#pragma unroll
        for (int i = 0; i < 4; ++i)
            af[i] = *(const int4v*)(As + ca + a_off + i * 1024);
#pragma unroll
        for (int j = 0; j < 8; ++j)
            bf[j] = *(const int4v*)(Bs + cb + b_off + j * 1024);

#pragma unroll
        for (int i = 0; i < 4; ++i)
#pragma unroll
            for (int j = 0; j < 8; ++j)
                acc[i][j] = __builtin_amdgcn_mfma_i32_16x16x64_i8(af[i], bf[j],
                                                                  acc[i][j], 0, 0, 0);

        __syncthreads();
    }

    // --- epilogue: C/D layout col=lane&15, row=(lane>>4)*4+reg (verified)
    const int gcol0 = bn * 256 + pn0 * 16 + (lane & 15);
    float ac8[8];
#pragma unroll
    for (int j = 0; j < 8; ++j) ac8[j] = (float)acol[gcol0 + j * 16];

    const size_t grow0 = (size_t)bm * 128 + pm0 * 16 + (lane >> 4) * 4;
#pragma unroll
    for (int i = 0; i < 4; ++i) {
#pragma unroll
        for (int r = 0; r < 4; ++r) {
            const size_t row = grow0 + i * 16 + r;
            const float ar = (float)arow[row];
            _Float16* outp = Cout + row * (size_t)N_DIM + gcol0;
#pragma unroll
            for (int j = 0; j < 8; ++j) {
                float v = (float)acc[i][j][r] * ar * ac8[j];
                outp[j * 16] = (_Float16)v;
            }
        }
    }
}

// ---------------------------------------------------------------------------
extern "C" void kernel_launch(void* const* d_in, const int* in_sizes, int n_in,
                              void* d_out, int out_size, void* d_ws, size_t ws_size,
                              hipStream_t stream) {
    const int* a = (const int*)d_in[0];             // [M,K] int32 (int8 values)
    const int* b = (const int*)d_in[1];             // [N,K] int32 (int8 values)
    const _Float16* ar = (const _Float16*)d_in[2];  // [M] fp16
    const _Float16* ac = (const _Float16*)d_in[3];  // [N] fp16
    _Float16* out = (_Float16*)d_out;               // [M,N] fp16

    unsigned char* pa = (unsigned char*)d_ws;        // 16 MB
    unsigned char* pb = pa + (size_t)M_DIM * K_DIM;  // 32 MB

    const size_t total_frag = (size_t)(M_DIM / 16 + N_DIM / 16) * (K_DIM / 64) * 64;
    pack_frag<<<(int)(total_frag / 256), 256, 0, stream>>>(a, b, pa, pb);

    dim3 grid(N_DIM / 256, M_DIM / 128);
    gemm_i8<<<grid, 256, 0, stream>>>(pa, pb, ar, ac, out);
}